// Round 20
// baseline (22.927 us; speedup 1.0000x reference)
//
#include <hip/hip_runtime.h>

typedef __attribute__((ext_vector_type(8)))  short short8;
typedef __attribute__((ext_vector_type(16))) float f32x16;

#define BATCH 8
#define NPTS  4096
#define NTS   8               // target splits per (dir,b)
#define TROWS (NPTS / NTS)    // 512 target rows per block
#define TPB   512             // 8 waves; each wave owns 32 query columns
#define NQG   16              // query groups of 256 per (dir,b)
#define NQTOT (2 * BATCH * NPTS)   // 65536 total queries
#define ONEB  0x3F80u         // bf16(1.0)
#define BIASB 0x4080u         // bf16(4.0)
#define BIASF 4.0f

// round-to-nearest-even f32 -> bf16 bits
__device__ __forceinline__ unsigned bfr(float f) {
    unsigned u = __float_as_uint(f);
    return (u + 0x7FFFu + ((u >> 16) & 1u)) >> 16;
}
__device__ __forceinline__ float ubf(unsigned s) {
    return __uint_as_float(s << 16);
}

// MFMA chamfer, round-20: NTS 4->8. 16 KiB LDS, 1 staged row/thread,
// 2048 blocks; with VGPR<=64 (r14's near-identical loop measured 52) this
// reaches 4 blocks/CU = 32 waves/CU — the occupancy cap — hiding the
// ds_read->MFMA->min3 latency chain and shrinking per-block prologue.
// Encoding unchanged (verified absmax 0.0 since r14): P = |t-q|^2 + BIAS,
// K=16 rank factorization, hi k0-7 (lanes<32), lo k8-15 (lanes>=32), one
// mfma_f32_32x32x16_bf16 per 32x32 tile, register v_min3_f32 reduce,
// plain coalesced partial stores (no atomics), K1-block0 zeroes out.
__global__ __launch_bounds__(TPB, 8) void chamfer_mfma(
    const float* __restrict__ preds,
    const float* __restrict__ gts,
    float* __restrict__ part,    // [NTS][NQTOT]
    float* __restrict__ out)
{
    const int blk = blockIdx.x;
    const int ts  = blk & (NTS - 1);
    const int qg  = (blk >> 3) & 15;
    const int db  = blk >> 7;        // dir*8 + b
    const int dir = db >> 3;
    const int b   = db & 7;

    if (blk == 0 && threadIdx.x == 0) out[0] = 0.0f;

    const float* Q = dir ? gts   : preds;   // query set (output-indexed)
    const float* T = dir ? preds : gts;     // target set (min'd over)

    __shared__ uint4 sA[2 * TROWS];  // [half][row] A-frags, 16 KiB

    const size_t bbase = (size_t)b * NPTS;
    const int lane = threadIdx.x & 63;
    const int wid  = threadIdx.x >> 6;
    const int la   = lane & 31;
    const int h    = lane >> 5;      // 0: k0-7 (hi), 1: k8-15 (lo)

    // ---- stage this block's 512 target rows as A-frags (1 row/thread,
    // lane-consecutive 16B ds_writes -> conflict-free)
    {
        const int r = threadIdx.x;
        const float* tp = T + (bbase + ts * TROWS + r) * 3;
        const float X = tp[0], Y = tp[1], Z = tp[2];
        const float px = -2.f * X, py = -2.f * Y, pz = -2.f * Z;
        const float rt = fmaf(X, X, fmaf(Y, Y, Z * Z));
        const unsigned pxh = bfr(px), pyh = bfr(py), pzh = bfr(pz);
        const unsigned pxl = bfr(px - ubf(pxh)), pyl = bfr(py - ubf(pyh)),
                       pzl = bfr(pz - ubf(pzh));
        const unsigned rth = bfr(rt), rtl = bfr(rt - ubf(rth));
        sA[r]         = make_uint4(pxh | (pyh << 16), pzh | (rth << 16),
                                   rtl | (ONEB << 16), ONEB | (ONEB << 16));
        sA[TROWS + r] = make_uint4(pxl | (pyl << 16), pzl | (pxh << 16),
                                   pyh | (pzh << 16), 0u);
    }

    // ---- this lane's B-frag: query col c, half h (k0-7 vs k8-15)
    short8 bfrag;
    const int c = qg * 256 + wid * 32 + la;
    {
        const float* qp = Q + (bbase + c) * 3;
        const float X = qp[0], Y = qp[1], Z = qp[2];
        const float rq = fmaf(X, X, fmaf(Y, Y, Z * Z));
        const unsigned xh = bfr(X), yh = bfr(Y), zh = bfr(Z);
        const unsigned xl = bfr(X - ubf(xh)), yl = bfr(Y - ubf(yh)),
                       zl = bfr(Z - ubf(zh));
        const unsigned rqh = bfr(rq), rql = bfr(rq - ubf(rqh));
        const uint4 b1 = make_uint4(xh | (yh << 16), zh | (ONEB << 16),
                                    ONEB | (rqh << 16), rql | (BIASB << 16));
        const uint4 b2 = make_uint4(xh | (yh << 16), zh | (xl << 16),
                                    yl | (zl << 16), 0u);
        bfrag = __builtin_bit_cast(short8, h ? b2 : b1);
    }

    __syncthreads();

    // ---- main loop: 16 target tiles, 2 per iter, register min3 reduce
    const f32x16 zacc = {};
    f32x16 macc;
    #pragma unroll
    for (int i = 0; i < 16; ++i) macc[i] = 3.4e38f;

    const uint4* aBase = sA + h * TROWS + la;
    for (int t = 0; t < TROWS / 32; t += 2) {
        const uint4 A0 = aBase[t * 32];
        const uint4 A1 = aBase[t * 32 + 32];
        const f32x16 p0 = __builtin_amdgcn_mfma_f32_32x32x16_bf16(
            __builtin_bit_cast(short8, A0), bfrag, zacc, 0, 0, 0);
        const f32x16 p1 = __builtin_amdgcn_mfma_f32_32x32x16_bf16(
            __builtin_bit_cast(short8, A1), bfrag, zacc, 0, 0, 0);
        #pragma unroll
        for (int i = 0; i < 16; ++i)
            macc[i] = fminf(fminf(p0[i], p1[i]), macc[i]);   // v_min3_f32
    }

    // ---- epilogue: min over the 16 row-slots, fold lane halves, store
    const float g0 = fminf(fminf(macc[0],  macc[1]),  macc[2]);
    const float g1 = fminf(fminf(macc[3],  macc[4]),  macc[5]);
    const float g2 = fminf(fminf(macc[6],  macc[7]),  macc[8]);
    const float g3 = fminf(fminf(macc[9],  macc[10]), macc[11]);
    const float g4 = fminf(fminf(macc[12], macc[13]), macc[14]);
    float m = fminf(fminf(fminf(g0, g1), fminf(g2, g3)),
                    fminf(g4, macc[15]));
    m = fminf(m, __shfl_xor(m, 32, 64));

    // coalesced partial store: part[ts][db*4096 + c]
    if (lane < 32)
        part[(size_t)ts * NQTOT + (size_t)db * NPTS + c] = m;
}

// Stage 2: one thread per query; min over the 8 target-split partials,
// subtract BIAS, block-reduce, one atomicAdd per block (out zeroed by K1).
#define TPB2 256
__global__ __launch_bounds__(TPB2) void chamfer_stage2(
    const float* __restrict__ part,
    float* __restrict__ out)
{
    const int g = blockIdx.x * TPB2 + threadIdx.x;   // [0, 65536)

    float m = part[g];
    #pragma unroll
    for (int s = 1; s < NTS; ++s)
        m = fminf(m, part[(size_t)s * NQTOT + g]);
    float s = m - BIASF;

    #pragma unroll
    for (int off = 32; off > 0; off >>= 1)
        s += __shfl_down(s, off, 64);

    __shared__ float red[TPB2 / 64];
    const int lane = threadIdx.x & 63;
    const int wid  = threadIdx.x >> 6;
    if (lane == 0) red[wid] = s;
    __syncthreads();
    if (threadIdx.x == 0) {
        float t = 0.0f;
        #pragma unroll
        for (int w = 0; w < TPB2 / 64; ++w) t += red[w];
        atomicAdd(out, t);
    }
}

extern "C" void kernel_launch(void* const* d_in, const int* in_sizes, int n_in,
                              void* d_out, int out_size, void* d_ws, size_t ws_size,
                              hipStream_t stream) {
    const float* preds = (const float*)d_in[0];
    const float* gts   = (const float*)d_in[1];
    float* out  = (float*)d_out;
    float* part = (float*)d_ws;   // NTS x 65536 floats = 2 MiB

    // 2 dispatches, no memsets: K1 block 0 zeroes out; part fully written
    // by K1 before K2 reads it (kernel-boundary visibility).
    chamfer_mfma<<<dim3(2 * BATCH * NQG * NTS), TPB, 0, stream>>>(preds, gts, part, out);
    chamfer_stage2<<<dim3(NQTOT / TPB2), TPB2, 0, stream>>>(part, out);
}

// Round 21
// 17.617 us; speedup vs baseline: 1.3014x; 1.3014x over previous
//
#include <hip/hip_runtime.h>

typedef __attribute__((ext_vector_type(8)))  short short8;
typedef __attribute__((ext_vector_type(16))) float f32x16;

#define BATCH 8
#define NPTS  4096
#define NTS   4               // target splits per (dir,b)  [r19 optimum]
#define TROWS (NPTS / NTS)    // 1024 target rows per block
#define TPB   512             // 8 waves; each wave owns 32 query columns
#define NQG   16              // query groups of 256 per (dir,b)
#define NQTOT (2 * BATCH * NPTS)   // 65536 total queries
#define ONEB  0x3F80u         // bf16(1.0)
#define BIASB 0x4080u         // bf16(4.0)
#define BIASF 4.0f

// round-to-nearest-even f32 -> bf16 bits
__device__ __forceinline__ unsigned bfr(float f) {
    unsigned u = __float_as_uint(f);
    return (u + 0x7FFFu + ((u >> 16) & 1u)) >> 16;
}
__device__ __forceinline__ float ubf(unsigned s) {
    return __uint_as_float(s << 16);
}

// MFMA chamfer — K1 is byte-identical to r19 (20.24 us, the occupancy
// optimum: NTS=4, 32 KiB LDS, 2 blocks/CU). Encoding verified absmax 0.0
// since r14: P = |t-q|^2 + BIAS, K=16 rank factorization, hi k0-7
// (lanes<32), lo k8-15 (lanes>=32), one mfma_f32_32x32x16_bf16 per tile,
// register v_min3_f32 reduce, plain coalesced partial stores, K1-block0
// zeroes out. Round-21 delta: K2 processes 4 queries/thread via float4
// (64 blocks, 1/4 the reduce instructions and atomics).
__global__ __launch_bounds__(TPB, 4) void chamfer_mfma(
    const float* __restrict__ preds,
    const float* __restrict__ gts,
    float* __restrict__ part,    // [NTS][NQTOT]
    float* __restrict__ out)
{
    const int blk = blockIdx.x;
    const int ts  = blk & (NTS - 1);
    const int qg  = (blk >> 2) & 15;
    const int db  = blk >> 6;        // dir*8 + b
    const int dir = db >> 3;
    const int b   = db & 7;

    if (blk == 0 && threadIdx.x == 0) out[0] = 0.0f;

    const float* Q = dir ? gts   : preds;   // query set (output-indexed)
    const float* T = dir ? preds : gts;     // target set (min'd over)

    __shared__ uint4 sA[2 * TROWS];  // [half][row] A-frags, 32 KiB

    const size_t bbase = (size_t)b * NPTS;
    const int lane = threadIdx.x & 63;
    const int wid  = threadIdx.x >> 6;
    const int la   = lane & 31;
    const int h    = lane >> 5;      // 0: k0-7 (hi), 1: k8-15 (lo)

    // ---- stage this block's 1024 target rows as A-frags (2 rows/thread,
    // lane-consecutive 16B ds_writes -> conflict-free)
    for (int j = 0; j < TROWS / TPB; ++j) {
        const int r = threadIdx.x + j * TPB;
        const float* tp = T + (bbase + ts * TROWS + r) * 3;
        const float X = tp[0], Y = tp[1], Z = tp[2];
        const float px = -2.f * X, py = -2.f * Y, pz = -2.f * Z;
        const float rt = fmaf(X, X, fmaf(Y, Y, Z * Z));
        const unsigned pxh = bfr(px), pyh = bfr(py), pzh = bfr(pz);
        const unsigned pxl = bfr(px - ubf(pxh)), pyl = bfr(py - ubf(pyh)),
                       pzl = bfr(pz - ubf(pzh));
        const unsigned rth = bfr(rt), rtl = bfr(rt - ubf(rth));
        sA[r]         = make_uint4(pxh | (pyh << 16), pzh | (rth << 16),
                                   rtl | (ONEB << 16), ONEB | (ONEB << 16));
        sA[TROWS + r] = make_uint4(pxl | (pyl << 16), pzl | (pxh << 16),
                                   pyh | (pzh << 16), 0u);
    }

    // ---- this lane's B-frag: query col c, half h (k0-7 vs k8-15)
    short8 bfrag;
    const int c = qg * 256 + wid * 32 + la;
    {
        const float* qp = Q + (bbase + c) * 3;
        const float X = qp[0], Y = qp[1], Z = qp[2];
        const float rq = fmaf(X, X, fmaf(Y, Y, Z * Z));
        const unsigned xh = bfr(X), yh = bfr(Y), zh = bfr(Z);
        const unsigned xl = bfr(X - ubf(xh)), yl = bfr(Y - ubf(yh)),
                       zl = bfr(Z - ubf(zh));
        const unsigned rqh = bfr(rq), rql = bfr(rq - ubf(rqh));
        const uint4 b1 = make_uint4(xh | (yh << 16), zh | (ONEB << 16),
                                    ONEB | (rqh << 16), rql | (BIASB << 16));
        const uint4 b2 = make_uint4(xh | (yh << 16), zh | (xl << 16),
                                    yl | (zl << 16), 0u);
        bfrag = __builtin_bit_cast(short8, h ? b2 : b1);
    }

    __syncthreads();

    // ---- main loop: 32 target tiles, 2 per iter, register min3 reduce
    const f32x16 zacc = {};
    f32x16 macc;
    #pragma unroll
    for (int i = 0; i < 16; ++i) macc[i] = 3.4e38f;

    const uint4* aBase = sA + h * TROWS + la;
    for (int t = 0; t < TROWS / 32; t += 2) {
        const uint4 A0 = aBase[t * 32];
        const uint4 A1 = aBase[t * 32 + 32];
        const f32x16 p0 = __builtin_amdgcn_mfma_f32_32x32x16_bf16(
            __builtin_bit_cast(short8, A0), bfrag, zacc, 0, 0, 0);
        const f32x16 p1 = __builtin_amdgcn_mfma_f32_32x32x16_bf16(
            __builtin_bit_cast(short8, A1), bfrag, zacc, 0, 0, 0);
        #pragma unroll
        for (int i = 0; i < 16; ++i)
            macc[i] = fminf(fminf(p0[i], p1[i]), macc[i]);   // v_min3_f32
    }

    // ---- epilogue: min over the 16 row-slots, fold lane halves, store
    const float g0 = fminf(fminf(macc[0],  macc[1]),  macc[2]);
    const float g1 = fminf(fminf(macc[3],  macc[4]),  macc[5]);
    const float g2 = fminf(fminf(macc[6],  macc[7]),  macc[8]);
    const float g3 = fminf(fminf(macc[9],  macc[10]), macc[11]);
    const float g4 = fminf(fminf(macc[12], macc[13]), macc[14]);
    float m = fminf(fminf(fminf(g0, g1), fminf(g2, g3)),
                    fminf(g4, macc[15]));
    m = fminf(m, __shfl_xor(m, 32, 64));

    // coalesced partial store: part[ts][db*4096 + c]
    if (lane < 32)
        part[(size_t)ts * NQTOT + (size_t)db * NPTS + c] = m;
}

// Stage 2: 4 queries/thread via float4; min over the 4 target-split
// partials (v_min3 fusion), subtract BIAS, block-reduce, one atomicAdd
// per block (64 blocks; out zeroed by K1).
#define TPB2 256
#define QP2  4
__global__ __launch_bounds__(TPB2) void chamfer_stage2(
    const float* __restrict__ part,
    float* __restrict__ out)
{
    const size_t g4 = (size_t)(blockIdx.x * TPB2 + threadIdx.x) * QP2;

    const float4 p0 = *reinterpret_cast<const float4*>(part + g4);
    const float4 p1 = *reinterpret_cast<const float4*>(part + NQTOT + g4);
    const float4 p2 = *reinterpret_cast<const float4*>(part + 2 * (size_t)NQTOT + g4);
    const float4 p3 = *reinterpret_cast<const float4*>(part + 3 * (size_t)NQTOT + g4);

    const float m0 = fminf(fminf(p0.x, p1.x), fminf(p2.x, p3.x));
    const float m1 = fminf(fminf(p0.y, p1.y), fminf(p2.y, p3.y));
    const float m2 = fminf(fminf(p0.z, p1.z), fminf(p2.z, p3.z));
    const float m3 = fminf(fminf(p0.w, p1.w), fminf(p2.w, p3.w));

    float s = (m0 + m1) + (m2 + m3) - 4.0f * BIASF;

    #pragma unroll
    for (int off = 32; off > 0; off >>= 1)
        s += __shfl_down(s, off, 64);

    __shared__ float red[TPB2 / 64];
    const int lane = threadIdx.x & 63;
    const int wid  = threadIdx.x >> 6;
    if (lane == 0) red[wid] = s;
    __syncthreads();
    if (threadIdx.x == 0) {
        float t = 0.0f;
        #pragma unroll
        for (int w = 0; w < TPB2 / 64; ++w) t += red[w];
        atomicAdd(out, t);
    }
}

extern "C" void kernel_launch(void* const* d_in, const int* in_sizes, int n_in,
                              void* d_out, int out_size, void* d_ws, size_t ws_size,
                              hipStream_t stream) {
    const float* preds = (const float*)d_in[0];
    const float* gts   = (const float*)d_in[1];
    float* out  = (float*)d_out;
    float* part = (float*)d_ws;   // NTS x 65536 floats = 1 MiB

    // 2 dispatches, no memsets: K1 block 0 zeroes out; part fully written
    // by K1 before K2 reads it (kernel-boundary visibility).
    chamfer_mfma<<<dim3(2 * BATCH * NQG * NTS), TPB, 0, stream>>>(preds, gts, part, out);
    chamfer_stage2<<<dim3(NQTOT / (TPB2 * QP2)), TPB2, 0, stream>>>(part, out);
}

// Round 22
// 17.188 us; speedup vs baseline: 1.3339x; 1.0250x over previous
//
#include <hip/hip_runtime.h>

typedef __attribute__((ext_vector_type(8)))  short short8;
typedef __attribute__((ext_vector_type(16))) float f32x16;

#define BATCH 8
#define NPTS  4096
#define NTS   4               // target splits per (dir,b)  [r19 optimum]
#define TROWS (NPTS / NTS)    // 1024 target rows per block
#define TPB   512             // 8 waves; each wave owns 64 query columns
#define NQG   8               // query groups of 512 per (dir,b)
#define NQTOT (2 * BATCH * NPTS)   // 65536 total queries
#define ONEB  0x3F80u         // bf16(1.0)
#define BIASB 0x4080u         // bf16(4.0)
#define BIASF 4.0f

// round-to-nearest-even f32 -> bf16 bits
__device__ __forceinline__ unsigned bfr(float f) {
    unsigned u = __float_as_uint(f);
    return (u + 0x7FFFu + ((u >> 16) & 1u)) >> 16;
}
__device__ __forceinline__ float ubf(unsigned s) {
    return __uint_as_float(s << 16);
}

// MFMA chamfer, round-22: clean ds-halving A/B at the r19/r21 optimum.
// Same NTS=4 / 32 KiB LDS / 2 blocks/CU; each wave now owns 64 queries
// (TWO B-frags), so one ds_read_b128 A-tile feeds TWO MFMAs: ds_read/CU
// 1024 -> 512 (LDS pipe 5.1 -> 2.6 us) with MFMA/min3 totals invariant.
// Encoding verified absmax 0.0 since r14: P = |t-q|^2 + BIAS, K=16 rank
// factorization, hi k0-7 (lanes<32), lo k8-15 (lanes>=32), register
// v_min3_f32 reduce, plain coalesced partial stores, K1-block0 zeroes out.
__global__ __launch_bounds__(TPB, 4) void chamfer_mfma(
    const float* __restrict__ preds,
    const float* __restrict__ gts,
    float* __restrict__ part,    // [NTS][NQTOT]
    float* __restrict__ out)
{
    const int blk = blockIdx.x;
    const int ts  = blk & (NTS - 1);
    const int qg  = (blk >> 2) & 7;
    const int db  = blk >> 5;        // dir*8 + b
    const int dir = db >> 3;
    const int b   = db & 7;

    if (blk == 0 && threadIdx.x == 0) out[0] = 0.0f;

    const float* Q = dir ? gts   : preds;   // query set (output-indexed)
    const float* T = dir ? preds : gts;     // target set (min'd over)

    __shared__ uint4 sA[2 * TROWS];  // [half][row] A-frags, 32 KiB

    const size_t bbase = (size_t)b * NPTS;
    const int lane = threadIdx.x & 63;
    const int wid  = threadIdx.x >> 6;
    const int la   = lane & 31;
    const int h    = lane >> 5;      // 0: k0-7 (hi), 1: k8-15 (lo)

    // ---- stage this block's 1024 target rows as A-frags (2 rows/thread,
    // lane-consecutive 16B ds_writes -> conflict-free)
    for (int j = 0; j < TROWS / TPB; ++j) {
        const int r = threadIdx.x + j * TPB;
        const float* tp = T + (bbase + ts * TROWS + r) * 3;
        const float X = tp[0], Y = tp[1], Z = tp[2];
        const float px = -2.f * X, py = -2.f * Y, pz = -2.f * Z;
        const float rt = fmaf(X, X, fmaf(Y, Y, Z * Z));
        const unsigned pxh = bfr(px), pyh = bfr(py), pzh = bfr(pz);
        const unsigned pxl = bfr(px - ubf(pxh)), pyl = bfr(py - ubf(pyh)),
                       pzl = bfr(pz - ubf(pzh));
        const unsigned rth = bfr(rt), rtl = bfr(rt - ubf(rth));
        sA[r]         = make_uint4(pxh | (pyh << 16), pzh | (rth << 16),
                                   rtl | (ONEB << 16), ONEB | (ONEB << 16));
        sA[TROWS + r] = make_uint4(pxl | (pyl << 16), pzl | (pxh << 16),
                                   pyh | (pzh << 16), 0u);
    }

    // ---- this lane's TWO B-frags: query cols c0 and c0+32, half h
    const int c0 = qg * 512 + wid * 64 + la;
    short8 bfA, bfB;
    #pragma unroll
    for (int f = 0; f < 2; ++f) {
        const float* qp = Q + (bbase + c0 + f * 32) * 3;
        const float X = qp[0], Y = qp[1], Z = qp[2];
        const float rq = fmaf(X, X, fmaf(Y, Y, Z * Z));
        const unsigned xh = bfr(X), yh = bfr(Y), zh = bfr(Z);
        const unsigned xl = bfr(X - ubf(xh)), yl = bfr(Y - ubf(yh)),
                       zl = bfr(Z - ubf(zh));
        const unsigned rqh = bfr(rq), rql = bfr(rq - ubf(rqh));
        const uint4 b1 = make_uint4(xh | (yh << 16), zh | (ONEB << 16),
                                    ONEB | (rqh << 16), rql | (BIASB << 16));
        const uint4 b2 = make_uint4(xh | (yh << 16), zh | (xl << 16),
                                    yl | (zl << 16), 0u);
        const short8 bf = __builtin_bit_cast(short8, h ? b2 : b1);
        if (f == 0) bfA = bf; else bfB = bf;
    }

    __syncthreads();

    // ---- main loop: 32 target tiles, 2 per iter; each A-read -> 2 MFMAs
    const f32x16 zacc = {};
    f32x16 maccA, maccB;
    #pragma unroll
    for (int i = 0; i < 16; ++i) { maccA[i] = 3.4e38f; maccB[i] = 3.4e38f; }

    const uint4* aBase = sA + h * TROWS + la;
    for (int t = 0; t < TROWS / 32; t += 2) {
        const uint4 A0 = aBase[t * 32];
        const uint4 A1 = aBase[t * 32 + 32];
        const f32x16 p0a = __builtin_amdgcn_mfma_f32_32x32x16_bf16(
            __builtin_bit_cast(short8, A0), bfA, zacc, 0, 0, 0);
        const f32x16 p1a = __builtin_amdgcn_mfma_f32_32x32x16_bf16(
            __builtin_bit_cast(short8, A1), bfA, zacc, 0, 0, 0);
        #pragma unroll
        for (int i = 0; i < 16; ++i)
            maccA[i] = fminf(fminf(p0a[i], p1a[i]), maccA[i]);  // v_min3_f32
        const f32x16 p0b = __builtin_amdgcn_mfma_f32_32x32x16_bf16(
            __builtin_bit_cast(short8, A0), bfB, zacc, 0, 0, 0);
        const f32x16 p1b = __builtin_amdgcn_mfma_f32_32x32x16_bf16(
            __builtin_bit_cast(short8, A1), bfB, zacc, 0, 0, 0);
        #pragma unroll
        for (int i = 0; i < 16; ++i)
            maccB[i] = fminf(fminf(p0b[i], p1b[i]), maccB[i]);
    }

    // ---- epilogue per frag: min over 16 row-slots, fold lane halves, store
    #define COLMIN(macc, mout) { \
        const float g0 = fminf(fminf(macc[0],  macc[1]),  macc[2]); \
        const float g1 = fminf(fminf(macc[3],  macc[4]),  macc[5]); \
        const float g2 = fminf(fminf(macc[6],  macc[7]),  macc[8]); \
        const float g3 = fminf(fminf(macc[9],  macc[10]), macc[11]); \
        const float g4 = fminf(fminf(macc[12], macc[13]), macc[14]); \
        mout = fminf(fminf(fminf(g0, g1), fminf(g2, g3)), \
                     fminf(g4, macc[15])); \
        mout = fminf(mout, __shfl_xor(mout, 32, 64)); }

    float mA, mB;
    COLMIN(maccA, mA)
    COLMIN(maccB, mB)
    #undef COLMIN

    if (lane < 32) {
        float* dst = part + (size_t)ts * NQTOT + (size_t)db * NPTS + c0;
        dst[0]  = mA;     // query c0
        dst[32] = mB;     // query c0+32
    }
}

// Stage 2: 4 queries/thread via float4; min over the 4 target-split
// partials (v_min3 fusion), subtract BIAS, block-reduce, one atomicAdd
// per block (64 blocks; out zeroed by K1).
#define TPB2 256
#define QP2  4
__global__ __launch_bounds__(TPB2) void chamfer_stage2(
    const float* __restrict__ part,
    float* __restrict__ out)
{
    const size_t g4 = (size_t)(blockIdx.x * TPB2 + threadIdx.x) * QP2;

    const float4 p0 = *reinterpret_cast<const float4*>(part + g4);
    const float4 p1 = *reinterpret_cast<const float4*>(part + NQTOT + g4);
    const float4 p2 = *reinterpret_cast<const float4*>(part + 2 * (size_t)NQTOT + g4);
    const float4 p3 = *reinterpret_cast<const float4*>(part + 3 * (size_t)NQTOT + g4);

    const float m0 = fminf(fminf(p0.x, p1.x), fminf(p2.x, p3.x));
    const float m1 = fminf(fminf(p0.y, p1.y), fminf(p2.y, p3.y));
    const float m2 = fminf(fminf(p0.z, p1.z), fminf(p2.z, p3.z));
    const float m3 = fminf(fminf(p0.w, p1.w), fminf(p2.w, p3.w));

    float s = (m0 + m1) + (m2 + m3) - 4.0f * BIASF;

    #pragma unroll
    for (int off = 32; off > 0; off >>= 1)
        s += __shfl_down(s, off, 64);

    __shared__ float red[TPB2 / 64];
    const int lane = threadIdx.x & 63;
    const int wid  = threadIdx.x >> 6;
    if (lane == 0) red[wid] = s;
    __syncthreads();
    if (threadIdx.x == 0) {
        float t = 0.0f;
        #pragma unroll
        for (int w = 0; w < TPB2 / 64; ++w) t += red[w];
        atomicAdd(out, t);
    }
}

extern "C" void kernel_launch(void* const* d_in, const int* in_sizes, int n_in,
                              void* d_out, int out_size, void* d_ws, size_t ws_size,
                              hipStream_t stream) {
    const float* preds = (const float*)d_in[0];
    const float* gts   = (const float*)d_in[1];
    float* out  = (float*)d_out;
    float* part = (float*)d_ws;   // NTS x 65536 floats = 1 MiB

    // 2 dispatches, no memsets: K1 block 0 zeroes out; part fully written
    // by K1 before K2 reads it (kernel-boundary visibility).
    chamfer_mfma<<<dim3(2 * BATCH * NQG * NTS), TPB, 0, stream>>>(preds, gts, part, out);
    chamfer_stage2<<<dim3(NQTOT / (TPB2 * QP2)), TPB2, 0, stream>>>(part, out);
}

// Round 23
// 17.145 us; speedup vs baseline: 1.3372x; 1.0025x over previous
//
#include <hip/hip_runtime.h>

typedef __attribute__((ext_vector_type(8)))  short short8;
typedef __attribute__((ext_vector_type(16))) float f32x16;

#define BATCH 8
#define NPTS  4096
#define NTS   4               // target splits per (dir,b)  [r19 optimum]
#define TROWS (NPTS / NTS)    // 1024 target rows per block
#define TPB   512             // 8 waves; each wave owns 64 query columns
#define NQG   8               // query groups of 512 per (dir,b)
#define NQTOT (2 * BATCH * NPTS)   // 65536 total queries
#define ONEB  0x3F80u         // bf16(1.0)
#define BIASB 0x4080u         // bf16(4.0)
#define BIASF 4.0f

// round-to-nearest-even f32 -> bf16 bits
__device__ __forceinline__ unsigned bfr(float f) {
    unsigned u = __float_as_uint(f);
    return (u + 0x7FFFu + ((u >> 16) & 1u)) >> 16;
}
__device__ __forceinline__ float ubf(unsigned s) {
    return __uint_as_float(s << 16);
}

// MFMA chamfer — r22 winner (17.19 us) + ONE change: s_setprio(1) around
// each MFMA cluster in the main loop (T5). The loop has no barriers and
// 4 waves/SIMD run phase-offset (MFMA cluster vs min3 cluster), the regime
// where setprio measured +4-7% (attn); null on barrier-locked loops.
// Encoding verified absmax 0.0 since r14: P = |t-q|^2 + BIAS, K=16 rank
// factorization, hi k0-7 (lanes<32), lo k8-15 (lanes>=32), one
// mfma_f32_32x32x16_bf16 per 32x32 tile, register v_min3_f32 reduce,
// plain coalesced partial stores, K1-block0 zeroes out.
__global__ __launch_bounds__(TPB, 4) void chamfer_mfma(
    const float* __restrict__ preds,
    const float* __restrict__ gts,
    float* __restrict__ part,    // [NTS][NQTOT]
    float* __restrict__ out)
{
    const int blk = blockIdx.x;
    const int ts  = blk & (NTS - 1);
    const int qg  = (blk >> 2) & 7;
    const int db  = blk >> 5;        // dir*8 + b
    const int dir = db >> 3;
    const int b   = db & 7;

    if (blk == 0 && threadIdx.x == 0) out[0] = 0.0f;

    const float* Q = dir ? gts   : preds;   // query set (output-indexed)
    const float* T = dir ? preds : gts;     // target set (min'd over)

    __shared__ uint4 sA[2 * TROWS];  // [half][row] A-frags, 32 KiB

    const size_t bbase = (size_t)b * NPTS;
    const int lane = threadIdx.x & 63;
    const int wid  = threadIdx.x >> 6;
    const int la   = lane & 31;
    const int h    = lane >> 5;      // 0: k0-7 (hi), 1: k8-15 (lo)

    // ---- stage this block's 1024 target rows as A-frags (2 rows/thread,
    // lane-consecutive 16B ds_writes -> conflict-free)
    for (int j = 0; j < TROWS / TPB; ++j) {
        const int r = threadIdx.x + j * TPB;
        const float* tp = T + (bbase + ts * TROWS + r) * 3;
        const float X = tp[0], Y = tp[1], Z = tp[2];
        const float px = -2.f * X, py = -2.f * Y, pz = -2.f * Z;
        const float rt = fmaf(X, X, fmaf(Y, Y, Z * Z));
        const unsigned pxh = bfr(px), pyh = bfr(py), pzh = bfr(pz);
        const unsigned pxl = bfr(px - ubf(pxh)), pyl = bfr(py - ubf(pyh)),
                       pzl = bfr(pz - ubf(pzh));
        const unsigned rth = bfr(rt), rtl = bfr(rt - ubf(rth));
        sA[r]         = make_uint4(pxh | (pyh << 16), pzh | (rth << 16),
                                   rtl | (ONEB << 16), ONEB | (ONEB << 16));
        sA[TROWS + r] = make_uint4(pxl | (pyl << 16), pzl | (pxh << 16),
                                   pyh | (pzh << 16), 0u);
    }

    // ---- this lane's TWO B-frags: query cols c0 and c0+32, half h
    const int c0 = qg * 512 + wid * 64 + la;
    short8 bfA, bfB;
    #pragma unroll
    for (int f = 0; f < 2; ++f) {
        const float* qp = Q + (bbase + c0 + f * 32) * 3;
        const float X = qp[0], Y = qp[1], Z = qp[2];
        const float rq = fmaf(X, X, fmaf(Y, Y, Z * Z));
        const unsigned xh = bfr(X), yh = bfr(Y), zh = bfr(Z);
        const unsigned xl = bfr(X - ubf(xh)), yl = bfr(Y - ubf(yh)),
                       zl = bfr(Z - ubf(zh));
        const unsigned rqh = bfr(rq), rql = bfr(rq - ubf(rqh));
        const uint4 b1 = make_uint4(xh | (yh << 16), zh | (ONEB << 16),
                                    ONEB | (rqh << 16), rql | (BIASB << 16));
        const uint4 b2 = make_uint4(xh | (yh << 16), zh | (xl << 16),
                                    yl | (zl << 16), 0u);
        const short8 bf = __builtin_bit_cast(short8, h ? b2 : b1);
        if (f == 0) bfA = bf; else bfB = bf;
    }

    __syncthreads();

    // ---- main loop: 32 target tiles, 2 per iter; each A-read -> 2 MFMAs;
    // setprio(1) around each MFMA cluster (waves run barrier-free,
    // phase-offset -> scheduler can favor the MFMA-issuing wave)
    const f32x16 zacc = {};
    f32x16 maccA, maccB;
    #pragma unroll
    for (int i = 0; i < 16; ++i) { maccA[i] = 3.4e38f; maccB[i] = 3.4e38f; }

    const uint4* aBase = sA + h * TROWS + la;
    for (int t = 0; t < TROWS / 32; t += 2) {
        const uint4 A0 = aBase[t * 32];
        const uint4 A1 = aBase[t * 32 + 32];
        __builtin_amdgcn_s_setprio(1);
        const f32x16 p0a = __builtin_amdgcn_mfma_f32_32x32x16_bf16(
            __builtin_bit_cast(short8, A0), bfA, zacc, 0, 0, 0);
        const f32x16 p1a = __builtin_amdgcn_mfma_f32_32x32x16_bf16(
            __builtin_bit_cast(short8, A1), bfA, zacc, 0, 0, 0);
        __builtin_amdgcn_s_setprio(0);
        #pragma unroll
        for (int i = 0; i < 16; ++i)
            maccA[i] = fminf(fminf(p0a[i], p1a[i]), maccA[i]);  // v_min3_f32
        __builtin_amdgcn_s_setprio(1);
        const f32x16 p0b = __builtin_amdgcn_mfma_f32_32x32x16_bf16(
            __builtin_bit_cast(short8, A0), bfB, zacc, 0, 0, 0);
        const f32x16 p1b = __builtin_amdgcn_mfma_f32_32x32x16_bf16(
            __builtin_bit_cast(short8, A1), bfB, zacc, 0, 0, 0);
        __builtin_amdgcn_s_setprio(0);
        #pragma unroll
        for (int i = 0; i < 16; ++i)
            maccB[i] = fminf(fminf(p0b[i], p1b[i]), maccB[i]);
    }

    // ---- epilogue per frag: min over 16 row-slots, fold lane halves, store
    #define COLMIN(macc, mout) { \
        const float g0 = fminf(fminf(macc[0],  macc[1]),  macc[2]); \
        const float g1 = fminf(fminf(macc[3],  macc[4]),  macc[5]); \
        const float g2 = fminf(fminf(macc[6],  macc[7]),  macc[8]); \
        const float g3 = fminf(fminf(macc[9],  macc[10]), macc[11]); \
        const float g4 = fminf(fminf(macc[12], macc[13]), macc[14]); \
        mout = fminf(fminf(fminf(g0, g1), fminf(g2, g3)), \
                     fminf(g4, macc[15])); \
        mout = fminf(mout, __shfl_xor(mout, 32, 64)); }

    float mA, mB;
    COLMIN(maccA, mA)
    COLMIN(maccB, mB)
    #undef COLMIN

    if (lane < 32) {
        float* dst = part + (size_t)ts * NQTOT + (size_t)db * NPTS + c0;
        dst[0]  = mA;     // query c0
        dst[32] = mB;     // query c0+32
    }
}

// Stage 2: 4 queries/thread via float4; min over the 4 target-split
// partials (v_min3 fusion), subtract BIAS, block-reduce, one atomicAdd
// per block (64 blocks; out zeroed by K1).
#define TPB2 256
#define QP2  4
__global__ __launch_bounds__(TPB2) void chamfer_stage2(
    const float* __restrict__ part,
    float* __restrict__ out)
{
    const size_t g4 = (size_t)(blockIdx.x * TPB2 + threadIdx.x) * QP2;

    const float4 p0 = *reinterpret_cast<const float4*>(part + g4);
    const float4 p1 = *reinterpret_cast<const float4*>(part + NQTOT + g4);
    const float4 p2 = *reinterpret_cast<const float4*>(part + 2 * (size_t)NQTOT + g4);
    const float4 p3 = *reinterpret_cast<const float4*>(part + 3 * (size_t)NQTOT + g4);

    const float m0 = fminf(fminf(p0.x, p1.x), fminf(p2.x, p3.x));
    const float m1 = fminf(fminf(p0.y, p1.y), fminf(p2.y, p3.y));
    const float m2 = fminf(fminf(p0.z, p1.z), fminf(p2.z, p3.z));
    const float m3 = fminf(fminf(p0.w, p1.w), fminf(p2.w, p3.w));

    float s = (m0 + m1) + (m2 + m3) - 4.0f * BIASF;

    #pragma unroll
    for (int off = 32; off > 0; off >>= 1)
        s += __shfl_down(s, off, 64);

    __shared__ float red[TPB2 / 64];
    const int lane = threadIdx.x & 63;
    const int wid  = threadIdx.x >> 6;
    if (lane == 0) red[wid] = s;
    __syncthreads();
    if (threadIdx.x == 0) {
        float t = 0.0f;
        #pragma unroll
        for (int w = 0; w < TPB2 / 64; ++w) t += red[w];
        atomicAdd(out, t);
    }
}

extern "C" void kernel_launch(void* const* d_in, const int* in_sizes, int n_in,
                              void* d_out, int out_size, void* d_ws, size_t ws_size,
                              hipStream_t stream) {
    const float* preds = (const float*)d_in[0];
    const float* gts   = (const float*)d_in[1];
    float* out  = (float*)d_out;
    float* part = (float*)d_ws;   // NTS x 65536 floats = 1 MiB

    // 2 dispatches, no memsets: K1 block 0 zeroes out; part fully written
    // by K1 before K2 reads it (kernel-boundary visibility).
    chamfer_mfma<<<dim3(2 * BATCH * NQG * NTS), TPB, 0, stream>>>(preds, gts, part, out);
    chamfer_stage2<<<dim3(NQTOT / (TPB2 * QP2)), TPB2, 0, stream>>>(part, out);
}